// Round 5
// baseline (441.563 us; speedup 1.0000x reference)
//
#include <hip/hip_runtime.h>
#include <hip/hip_bf16.h>
#include <hip/hip_fp16.h>
#include <math.h>

// GraphEncoderStack: 2x (GCNConv -> BN -> ReLU) + residual + 2 GCN heads + reparam
// N=50000 nodes, E=800000 edges, IN=HIDDEN=128, LATENT=32.
// fp32 math; GEMM->prop intermediates bf16; CSR record = 4B {src:16, fp16 u}.
// Requires n < 65536 (problem fixes n=50000).

#define HID 128
#define LAT 32

// ---------------- degree+count in one packed 64-bit atomic ----------------
// packed[d] += (1<<48) | (w * 2^24). Count in hi16, fixed-point weight sum in
// low 48 (max sum 2^24, exact integer adds -> order-independent/deterministic).

__global__ __launch_bounds__(256) void k_deg_edges(const int* __restrict__ dst,
    const float* __restrict__ w, unsigned long long* __restrict__ packed, int E) {
  int e = blockIdx.x * 256 + threadIdx.x;
  if (e < E) {
    int d = dst[e];
    unsigned long long v =
        (1ULL << 48) | (unsigned long long)(w[e] * 16777216.0f);
    atomicAdd(&packed[d], v);
  }
}

__global__ __launch_bounds__(256) void k_dinv(
    const unsigned long long* __restrict__ packed, float* __restrict__ dinv,
    int* __restrict__ cnt, int n) {
  int i = blockIdx.x * 256 + threadIdx.x;
  if (i < n) {
    unsigned long long p = packed[i];
    cnt[i] = (int)(p >> 48);
    float d = (float)(p & 0xFFFFFFFFFFFFULL) * (1.0f / 16777216.0f) + 1.0f;
    dinv[i] = rsqrtf(d);  // d >= 1 (self loop)
  }
}

// ---------------- hierarchical exclusive scan (n <= 65536) ----------------
#define SCH 1024

__global__ __launch_bounds__(256) void k_scan_part(const int* __restrict__ cnt,
    int* __restrict__ bsum, int n) {
  int base = blockIdx.x * SCH + threadIdx.x * 4;
  int4 v = make_int4(0, 0, 0, 0);
  if (base + 3 < n) v = *(const int4*)&cnt[base];
  else {
    if (base + 0 < n) v.x = cnt[base + 0];
    if (base + 1 < n) v.y = cnt[base + 1];
    if (base + 2 < n) v.z = cnt[base + 2];
  }
  int s = v.x + v.y + v.z + v.w;
#pragma unroll
  for (int off = 32; off; off >>= 1) s += __shfl_down(s, off);
  __shared__ int ws[4];
  if ((threadIdx.x & 63) == 0) ws[threadIdx.x >> 6] = s;
  __syncthreads();
  if (threadIdx.x == 0) bsum[blockIdx.x] = ws[0] + ws[1] + ws[2] + ws[3];
}

__global__ __launch_bounds__(64) void k_scan_mid(const int* __restrict__ bsum,
    int* __restrict__ boff, int* __restrict__ off, int nb, int n) {
  int t = threadIdx.x;
  int val = (t < nb) ? bsum[t] : 0;
  int inc = val;
#pragma unroll
  for (int d = 1; d < 64; d <<= 1) {
    int u = __shfl_up(inc, d);
    if (t >= d) inc += u;
  }
  if (t < nb) boff[t] = inc - val;
  if (t == nb - 1) off[n] = inc;
}

__global__ __launch_bounds__(256) void k_scan_out(const int* __restrict__ cnt,
    const int* __restrict__ boff, int* __restrict__ off, int* __restrict__ pos,
    int n) {
  int base = blockIdx.x * SCH + threadIdx.x * 4;
  int4 v = make_int4(0, 0, 0, 0);
  if (base + 3 < n) v = *(const int4*)&cnt[base];
  else {
    if (base + 0 < n) v.x = cnt[base + 0];
    if (base + 1 < n) v.y = cnt[base + 1];
    if (base + 2 < n) v.z = cnt[base + 2];
  }
  int s = v.x + v.y + v.z + v.w;
  int lane = threadIdx.x & 63, wv = threadIdx.x >> 6;
  int inc = s;
#pragma unroll
  for (int d = 1; d < 64; d <<= 1) {
    int u = __shfl_up(inc, d);
    if (lane >= d) inc += u;
  }
  __shared__ int wsum[4];
  if (lane == 63) wsum[wv] = inc;
  __syncthreads();
  int wbase = 0;
  for (int i = 0; i < wv; ++i) wbase += wsum[i];
  int ex = boff[blockIdx.x] + wbase + inc - s;
  int4 o = make_int4(ex, ex + v.x, ex + v.x + v.y, ex + v.x + v.y + v.z);
  if (base + 3 < n) {
    *(int4*)&off[base] = o;
    *(int4*)&pos[base] = o;
  } else {
    if (base + 0 < n) { off[base + 0] = o.x; pos[base + 0] = o.x; }
    if (base + 1 < n) { off[base + 1] = o.y; pos[base + 1] = o.y; }
    if (base + 2 < n) { off[base + 2] = o.z; pos[base + 2] = o.z; }
  }
}

// CSR record: 4B = (src << 16) | fp16(w * dinv[src]).  dinv[dst] factored
// into prop epilogue.
__global__ __launch_bounds__(256) void k_fill(const int* __restrict__ src,
    const int* __restrict__ dst, const float* __restrict__ w,
    const float* __restrict__ dinv, int* __restrict__ pos,
    unsigned int* __restrict__ erec, int E) {
  int e = blockIdx.x * 256 + threadIdx.x;
  if (e < E) {
    int s = src[e], d = dst[e];
    int p = atomicAdd(&pos[d], 1);
    __half u = __float2half(w[e] * dinv[s]);
    erec[p] = ((unsigned)s << 16) | (unsigned)__half_as_ushort(u);
  }
}

// ---------------- fp32 GEMM -> bf16 output, K=128, NOUT in {128, 64} -------
// 32-row LDS tile; MODE 0 plain; MODE 1 bn+relu on load + residual
// side-write; MODE 2 bn+relu+residual add on load.

__device__ __forceinline__ unsigned bf2(float a, float b) {
  unsigned ua = __float_as_uint(a);
  ua += 0x7FFFu + ((ua >> 16) & 1u);
  unsigned ub = __float_as_uint(b);
  ub += 0x7FFFu + ((ub >> 16) & 1u);
  return (ua >> 16) | (ub & 0xFFFF0000u);
}

#define TMG 32
template <int NOUT, int MODE>
__global__ __launch_bounds__(256) void k_gemm(const float* __restrict__ X,
    const float* __restrict__ W, unsigned short* __restrict__ Y, int n,
    const float* __restrict__ scsh, const float4* __restrict__ Rres,
    float4* __restrict__ Rout) {
  constexpr int NCT = NOUT / 8;
  constexpr int NRG = 256 / NCT;
  constexpr int RPT = TMG / NRG;
  constexpr int LDSTR = 132;
  __shared__ float xs[TMG * LDSTR];
  const int t = threadIdx.x;
  const int ct = t % NCT;
  const int rg = t / NCT;
  const int c = ct * 8;
  const int row0 = blockIdx.x * TMG;
  for (int i = t; i < TMG * 32; i += 256) {
    int r = i >> 5, q = i & 31;
    bool valid = (row0 + r) < n;
    float4 v = valid ? ((const float4*)X)[(size_t)(row0 + r) * 32 + q]
                     : make_float4(0.f, 0.f, 0.f, 0.f);
    if (MODE >= 1) {
      int c0 = q * 4;
      v.x = fmaxf(v.x * scsh[c0 + 0] + scsh[128 + c0 + 0], 0.f);
      v.y = fmaxf(v.y * scsh[c0 + 1] + scsh[128 + c0 + 1], 0.f);
      v.z = fmaxf(v.z * scsh[c0 + 2] + scsh[128 + c0 + 2], 0.f);
      v.w = fmaxf(v.w * scsh[c0 + 3] + scsh[128 + c0 + 3], 0.f);
      if (MODE == 2 && valid) {
        float4 rr = Rres[(size_t)(row0 + r) * 32 + q];
        v.x += rr.x; v.y += rr.y; v.z += rr.z; v.w += rr.w;
      }
      if (MODE == 1 && valid) Rout[(size_t)(row0 + r) * 32 + q] = v;
    }
    *(float4*)&xs[r * LDSTR + q * 4] = v;
  }
  __syncthreads();
  float acc[RPT][8];
#pragma unroll
  for (int i = 0; i < RPT; ++i)
#pragma unroll
    for (int j = 0; j < 8; ++j) acc[i][j] = 0.f;

#pragma unroll 4
  for (int k = 0; k < 128; k += 4) {
    float4 wa[4], wb[4];
#pragma unroll
    for (int kk = 0; kk < 4; ++kk) {
      wa[kk] = *(const float4*)&W[(size_t)(k + kk) * NOUT + c];
      wb[kk] = *(const float4*)&W[(size_t)(k + kk) * NOUT + c + 4];
    }
#pragma unroll
    for (int ri = 0; ri < RPT; ++ri) {
      const int rl = rg * RPT + ri;
      float4 xv = *(const float4*)&xs[rl * LDSTR + k];
      acc[ri][0] = fmaf(xv.x, wa[0].x, acc[ri][0]);
      acc[ri][1] = fmaf(xv.x, wa[0].y, acc[ri][1]);
      acc[ri][2] = fmaf(xv.x, wa[0].z, acc[ri][2]);
      acc[ri][3] = fmaf(xv.x, wa[0].w, acc[ri][3]);
      acc[ri][4] = fmaf(xv.x, wb[0].x, acc[ri][4]);
      acc[ri][5] = fmaf(xv.x, wb[0].y, acc[ri][5]);
      acc[ri][6] = fmaf(xv.x, wb[0].z, acc[ri][6]);
      acc[ri][7] = fmaf(xv.x, wb[0].w, acc[ri][7]);
      acc[ri][0] = fmaf(xv.y, wa[1].x, acc[ri][0]);
      acc[ri][1] = fmaf(xv.y, wa[1].y, acc[ri][1]);
      acc[ri][2] = fmaf(xv.y, wa[1].z, acc[ri][2]);
      acc[ri][3] = fmaf(xv.y, wa[1].w, acc[ri][3]);
      acc[ri][4] = fmaf(xv.y, wb[1].x, acc[ri][4]);
      acc[ri][5] = fmaf(xv.y, wb[1].y, acc[ri][5]);
      acc[ri][6] = fmaf(xv.y, wb[1].z, acc[ri][6]);
      acc[ri][7] = fmaf(xv.y, wb[1].w, acc[ri][7]);
      acc[ri][0] = fmaf(xv.z, wa[2].x, acc[ri][0]);
      acc[ri][1] = fmaf(xv.z, wa[2].y, acc[ri][1]);
      acc[ri][2] = fmaf(xv.z, wa[2].z, acc[ri][2]);
      acc[ri][3] = fmaf(xv.z, wa[2].w, acc[ri][3]);
      acc[ri][4] = fmaf(xv.z, wb[2].x, acc[ri][4]);
      acc[ri][5] = fmaf(xv.z, wb[2].y, acc[ri][5]);
      acc[ri][6] = fmaf(xv.z, wb[2].z, acc[ri][6]);
      acc[ri][7] = fmaf(xv.z, wb[2].w, acc[ri][7]);
      acc[ri][0] = fmaf(xv.w, wa[3].x, acc[ri][0]);
      acc[ri][1] = fmaf(xv.w, wa[3].y, acc[ri][1]);
      acc[ri][2] = fmaf(xv.w, wa[3].z, acc[ri][2]);
      acc[ri][3] = fmaf(xv.w, wa[3].w, acc[ri][3]);
      acc[ri][4] = fmaf(xv.w, wb[3].x, acc[ri][4]);
      acc[ri][5] = fmaf(xv.w, wb[3].y, acc[ri][5]);
      acc[ri][6] = fmaf(xv.w, wb[3].z, acc[ri][6]);
      acc[ri][7] = fmaf(xv.w, wb[3].w, acc[ri][7]);
    }
  }
#pragma unroll
  for (int ri = 0; ri < RPT; ++ri) {
    int r = row0 + rg * RPT + ri;
    if (r < n) {
      uint4 pk;
      pk.x = bf2(acc[ri][0], acc[ri][1]);
      pk.y = bf2(acc[ri][2], acc[ri][3]);
      pk.z = bf2(acc[ri][4], acc[ri][5]);
      pk.w = bf2(acc[ri][6], acc[ri][7]);
      *(uint4*)&Y[(size_t)r * NOUT + c] = pk;
    }
  }
}

// ------------- CSR propagation over bf16 rows: out fp32 ----------------
// out[d] = di * (sum_e u_e*T[src_e] + di*T[d]) + bias,  di = dinv[d].
template <int F>
__global__ __launch_bounds__(256) void k_propb(const uint4* __restrict__ T,
    const float* __restrict__ dinv, const int* __restrict__ off,
    const unsigned int* __restrict__ erec, const float* __restrict__ bias,
    float* __restrict__ out, int n) {
  constexpr int TPN = F / 8;
  constexpr int NPB = 256 / TPN;
  int node = blockIdx.x * NPB + threadIdx.x / TPN;
  int f8 = threadIdx.x % TPN;
  if (node >= n) return;
  float di = dinv[node];
  float acc[8];
  {
    uint4 v = T[(size_t)node * TPN + f8];
    acc[0] = di * __uint_as_float(v.x << 16);
    acc[1] = di * __uint_as_float(v.x & 0xFFFF0000u);
    acc[2] = di * __uint_as_float(v.y << 16);
    acc[3] = di * __uint_as_float(v.y & 0xFFFF0000u);
    acc[4] = di * __uint_as_float(v.z << 16);
    acc[5] = di * __uint_as_float(v.z & 0xFFFF0000u);
    acc[6] = di * __uint_as_float(v.w << 16);
    acc[7] = di * __uint_as_float(v.w & 0xFFFF0000u);
  }
  int e = off[node], eend = off[node + 1];
  for (; e + 1 < eend; e += 2) {
    unsigned r0 = erec[e], r1 = erec[e + 1];
    uint4 v0 = T[(size_t)(r0 >> 16) * TPN + f8];
    uint4 v1 = T[(size_t)(r1 >> 16) * TPN + f8];
    float n0 = __half2float(__ushort_as_half((unsigned short)(r0 & 0xFFFFu)));
    float n1 = __half2float(__ushort_as_half((unsigned short)(r1 & 0xFFFFu)));
    acc[0] = fmaf(n0, __uint_as_float(v0.x << 16), acc[0]);
    acc[1] = fmaf(n0, __uint_as_float(v0.x & 0xFFFF0000u), acc[1]);
    acc[2] = fmaf(n0, __uint_as_float(v0.y << 16), acc[2]);
    acc[3] = fmaf(n0, __uint_as_float(v0.y & 0xFFFF0000u), acc[3]);
    acc[4] = fmaf(n0, __uint_as_float(v0.z << 16), acc[4]);
    acc[5] = fmaf(n0, __uint_as_float(v0.z & 0xFFFF0000u), acc[5]);
    acc[6] = fmaf(n0, __uint_as_float(v0.w << 16), acc[6]);
    acc[7] = fmaf(n0, __uint_as_float(v0.w & 0xFFFF0000u), acc[7]);
    acc[0] = fmaf(n1, __uint_as_float(v1.x << 16), acc[0]);
    acc[1] = fmaf(n1, __uint_as_float(v1.x & 0xFFFF0000u), acc[1]);
    acc[2] = fmaf(n1, __uint_as_float(v1.y << 16), acc[2]);
    acc[3] = fmaf(n1, __uint_as_float(v1.y & 0xFFFF0000u), acc[3]);
    acc[4] = fmaf(n1, __uint_as_float(v1.z << 16), acc[4]);
    acc[5] = fmaf(n1, __uint_as_float(v1.z & 0xFFFF0000u), acc[5]);
    acc[6] = fmaf(n1, __uint_as_float(v1.w << 16), acc[6]);
    acc[7] = fmaf(n1, __uint_as_float(v1.w & 0xFFFF0000u), acc[7]);
  }
  if (e < eend) {
    unsigned r0 = erec[e];
    uint4 v0 = T[(size_t)(r0 >> 16) * TPN + f8];
    float n0 = __half2float(__ushort_as_half((unsigned short)(r0 & 0xFFFFu)));
    acc[0] = fmaf(n0, __uint_as_float(v0.x << 16), acc[0]);
    acc[1] = fmaf(n0, __uint_as_float(v0.x & 0xFFFF0000u), acc[1]);
    acc[2] = fmaf(n0, __uint_as_float(v0.y << 16), acc[2]);
    acc[3] = fmaf(n0, __uint_as_float(v0.y & 0xFFFF0000u), acc[3]);
    acc[4] = fmaf(n0, __uint_as_float(v0.z << 16), acc[4]);
    acc[5] = fmaf(n0, __uint_as_float(v0.z & 0xFFFF0000u), acc[5]);
    acc[6] = fmaf(n0, __uint_as_float(v0.w << 16), acc[6]);
    acc[7] = fmaf(n0, __uint_as_float(v0.w & 0xFFFF0000u), acc[7]);
  }
  float4 b0 = *(const float4*)&bias[f8 * 8];
  float4 b1 = *(const float4*)&bias[f8 * 8 + 4];
  float* op = &out[(size_t)node * F + f8 * 8];
  *(float4*)op = make_float4(fmaf(di, acc[0], b0.x), fmaf(di, acc[1], b0.y),
                             fmaf(di, acc[2], b0.z), fmaf(di, acc[3], b0.w));
  *(float4*)(op + 4) = make_float4(fmaf(di, acc[4], b1.x), fmaf(di, acc[5], b1.y),
                                   fmaf(di, acc[6], b1.z), fmaf(di, acc[7], b1.w));
}

// ---------------- BatchNorm stats ----------------

__global__ __launch_bounds__(128) void k_stats(const float* __restrict__ X,
    float* __restrict__ stats, int n) {
  int col = threadIdx.x;
  float s = 0.f, s2 = 0.f;
  for (int r = blockIdx.x; r < n; r += gridDim.x) {
    float v = X[(size_t)r * 128 + col];
    s += v; s2 += v * v;
  }
  atomicAdd(&stats[col], s);
  atomicAdd(&stats[128 + col], s2);
}

__global__ __launch_bounds__(128) void k_bnfin(const float* __restrict__ stats,
    const float* __restrict__ g, const float* __restrict__ be,
    float* __restrict__ scsh, int n) {
  int c = threadIdx.x;
  float m = stats[c] / (float)n;
  float var = stats[128 + c] / (float)n - m * m;
  var = fmaxf(var, 0.f);
  float sc = g[c] * rsqrtf(var + 1e-5f);
  scsh[c] = sc;
  scsh[128 + c] = be[c] - m * sc;
}

// ---------------- head weight concat + final reparam ----------------

__global__ __launch_bounds__(256) void k_concat(const float* __restrict__ Wm,
    const float* __restrict__ bm, const float* __restrict__ Ws,
    const float* __restrict__ bs, float* __restrict__ wcat,
    float* __restrict__ bcat) {
  int t = blockIdx.x * 256 + threadIdx.x;
  if (t < 128 * 64) {
    int k = t / 64, c = t % 64;
    wcat[t] = (c < 32) ? Wm[k * 32 + c] : Ws[k * 32 + (c - 32)];
  } else if (t < 128 * 64 + 64) {
    int c = t - 128 * 64;
    bcat[c] = (c < 32) ? bm[c] : bs[c - 32];
  }
}

__global__ __launch_bounds__(256) void k_final(const float* __restrict__ agg,
    const float* __restrict__ eps, float* __restrict__ out, int n) {
  int i = blockIdx.x * 256 + threadIdx.x;
  int M = n * 32;
  if (i >= M) return;
  int node = i >> 5, j = i & 31;
  float qm = agg[(size_t)node * 64 + j];
  float qs = agg[(size_t)node * 64 + 32 + j];
  float sp = fmaxf(qs, 0.f) + log1pf(expf(-fabsf(qs)));
  float stdv = sp + 1e-6f;
  out[i] = qm + stdv * eps[i];
  out[M + i] = qm;
  out[2 * M + i] = qs;
}

// ---------------- launch ----------------

extern "C" void kernel_launch(void* const* d_in, const int* in_sizes, int n_in,
                              void* d_out, int out_size, void* d_ws, size_t ws_size,
                              hipStream_t stream) {
  const float* x  = (const float*)d_in[0];
  const int*   ei = (const int*)d_in[1];
  const float* ew = (const float*)d_in[2];
  const float* W0 = (const float*)d_in[3];
  const float* b0 = (const float*)d_in[4];
  const float* W1 = (const float*)d_in[5];
  const float* b1 = (const float*)d_in[6];
  const float* g0 = (const float*)d_in[7];
  const float* be0 = (const float*)d_in[8];
  const float* g1 = (const float*)d_in[9];
  const float* be1 = (const float*)d_in[10];
  const float* Wm = (const float*)d_in[11];
  const float* bm = (const float*)d_in[12];
  const float* Ws = (const float*)d_in[13];
  const float* bs = (const float*)d_in[14];
  const float* eps = (const float*)d_in[15];
  float* out = (float*)d_out;

  const int n = in_sizes[0] / HID;
  const int E = in_sizes[1] / 2;
  const int* esrc = ei;
  const int* edst = ei + E;

  char* base = (char*)d_ws;
  size_t cur = 0;
  auto alloc = [&](size_t bytes) {
    size_t o = cur;
    cur = (cur + bytes + 255) & ~(size_t)255;
    return (void*)(base + o);
  };
  unsigned long long* packed = (unsigned long long*)alloc((size_t)n * 8);
  float* dinv  = (float*)alloc((size_t)n * 4);
  int*   cnt   = (int*)alloc((size_t)n * 4);
  int*   coff  = (int*)alloc((size_t)(n + 1) * 4);
  int*   cpos  = (int*)alloc((size_t)n * 4);
  unsigned int* erec = (unsigned int*)alloc((size_t)E * 4);
  int*   bsum  = (int*)alloc(64 * 4);
  int*   boff  = (int*)alloc(64 * 4);
  float* stats = (float*)alloc(256 * 4);
  float* scsh0 = (float*)alloc(256 * 4);
  float* scsh1 = (float*)alloc(256 * 4);
  float* wcat  = (float*)alloc(128 * 64 * 4);
  float* bcat  = (float*)alloc(64 * 4);
  unsigned short* bufA = (unsigned short*)alloc((size_t)n * 128 * 2);  // bf16
  float* bufB  = (float*)alloc((size_t)n * 128 * 4);
  float* bufC  = (float*)alloc((size_t)n * 128 * 4);
  (void)ws_size;

  const int nb = (n + 255) / 256;
  const int eb = (E + 255) / 256;
  const int gemmb = (n + TMG - 1) / TMG;
  const int scb = (n + SCH - 1) / SCH;
  const int mlat = n * 32;
  const int mlatb = (mlat + 255) / 256;

  // --- norm + CSR ---
  hipMemsetAsync(packed, 0, (size_t)n * 8, stream);
  k_deg_edges<<<eb, 256, 0, stream>>>(edst, ew, packed, E);
  k_dinv<<<nb, 256, 0, stream>>>(packed, dinv, cnt, n);
  k_scan_part<<<scb, 256, 0, stream>>>(cnt, bsum, n);
  k_scan_mid<<<1, 64, 0, stream>>>(bsum, boff, coff, scb, n);
  k_scan_out<<<scb, 256, 0, stream>>>(cnt, boff, coff, cpos, n);
  k_fill<<<eb, 256, 0, stream>>>(esrc, edst, ew, dinv, cpos, erec, E);
  k_concat<<<(128 * 64 + 64 + 255) / 256, 256, 0, stream>>>(Wm, bm, Ws, bs, wcat, bcat);

  // --- layer 0 ---
  k_gemm<128, 0><<<gemmb, 256, 0, stream>>>(x, W0, bufA, n, nullptr, nullptr, nullptr);
  k_propb<128><<<(n + 15) / 16, 256, 0, stream>>>((const uint4*)bufA, dinv, coff,
                                                  erec, b0, bufB, n);
  hipMemsetAsync(stats, 0, 256 * 4, stream);
  k_stats<<<512, 128, 0, stream>>>(bufB, stats, n);
  k_bnfin<<<1, 128, 0, stream>>>(stats, g0, be0, scsh0, n);

  // --- layer 1 (bn0+relu fused into gemm load; residual h0 -> bufC) ---
  k_gemm<128, 1><<<gemmb, 256, 0, stream>>>(bufB, W1, bufA, n, scsh0, nullptr,
                                            (float4*)bufC);
  k_propb<128><<<(n + 15) / 16, 256, 0, stream>>>((const uint4*)bufA, dinv, coff,
                                                  erec, b1, bufB, n);
  hipMemsetAsync(stats, 0, 256 * 4, stream);
  k_stats<<<512, 128, 0, stream>>>(bufB, stats, n);
  k_bnfin<<<1, 128, 0, stream>>>(stats, g1, be1, scsh1, n);

  // --- heads (bn1+relu+residual fused into gemm load; mean||logstd) ---
  k_gemm<64, 2><<<gemmb, 256, 0, stream>>>(bufB, wcat, bufA, n, scsh1,
                                           (const float4*)bufC, nullptr);
  k_propb<64><<<(n + 31) / 32, 256, 0, stream>>>((const uint4*)bufA, dinv, coff,
                                                 erec, bcat, bufB, n);

  // --- reparameterization + output ---
  k_final<<<mlatb, 256, 0, stream>>>(bufB, eps, out, n);
}

// Round 6
// 320.179 us; speedup vs baseline: 1.3791x; 1.3791x over previous
//
#include <hip/hip_runtime.h>
#include <hip/hip_bf16.h>
#include <hip/hip_fp16.h>
#include <math.h>

// GraphEncoderStack: 2x (GCNConv -> BN -> ReLU) + residual + 2 GCN heads + reparam
// N=50000 nodes, E=800000 edges, IN=HIDDEN=128, LATENT=32.
// fp32 math; GEMM via MFMA f16 (fp32 accum); features/records fp16.
// Requires n < 65536 (problem fixes n=50000).

#define HID 128
#define LAT 32

typedef _Float16 f16x8 __attribute__((ext_vector_type(8)));
typedef float f32x4 __attribute__((ext_vector_type(4)));

// ---------------- degree+count in one packed 64-bit atomic ----------------

__global__ __launch_bounds__(256) void k_deg_edges(const int* __restrict__ dst,
    const float* __restrict__ w, unsigned long long* __restrict__ packed, int E) {
  int e = blockIdx.x * 256 + threadIdx.x;
  if (e < E) {
    int d = dst[e];
    unsigned long long v =
        (1ULL << 48) | (unsigned long long)(w[e] * 16777216.0f);
    atomicAdd(&packed[d], v);
  }
}

__global__ __launch_bounds__(256) void k_dinv(
    const unsigned long long* __restrict__ packed, float* __restrict__ dinv,
    int* __restrict__ cnt, int n) {
  int i = blockIdx.x * 256 + threadIdx.x;
  if (i < n) {
    unsigned long long p = packed[i];
    cnt[i] = (int)(p >> 48);
    float d = (float)(p & 0xFFFFFFFFFFFFULL) * (1.0f / 16777216.0f) + 1.0f;
    dinv[i] = rsqrtf(d);
  }
}

// ---------------- hierarchical exclusive scan (n <= 65536) ----------------
#define SCH 1024

__global__ __launch_bounds__(256) void k_scan_part(const int* __restrict__ cnt,
    int* __restrict__ bsum, int n) {
  int base = blockIdx.x * SCH + threadIdx.x * 4;
  int4 v = make_int4(0, 0, 0, 0);
  if (base + 3 < n) v = *(const int4*)&cnt[base];
  else {
    if (base + 0 < n) v.x = cnt[base + 0];
    if (base + 1 < n) v.y = cnt[base + 1];
    if (base + 2 < n) v.z = cnt[base + 2];
  }
  int s = v.x + v.y + v.z + v.w;
#pragma unroll
  for (int off = 32; off; off >>= 1) s += __shfl_down(s, off);
  __shared__ int ws[4];
  if ((threadIdx.x & 63) == 0) ws[threadIdx.x >> 6] = s;
  __syncthreads();
  if (threadIdx.x == 0) bsum[blockIdx.x] = ws[0] + ws[1] + ws[2] + ws[3];
}

__global__ __launch_bounds__(64) void k_scan_mid(const int* __restrict__ bsum,
    int* __restrict__ boff, int* __restrict__ off, int nb, int n) {
  int t = threadIdx.x;
  int val = (t < nb) ? bsum[t] : 0;
  int inc = val;
#pragma unroll
  for (int d = 1; d < 64; d <<= 1) {
    int u = __shfl_up(inc, d);
    if (t >= d) inc += u;
  }
  if (t < nb) boff[t] = inc - val;
  if (t == nb - 1) off[n] = inc;
}

__global__ __launch_bounds__(256) void k_scan_out(const int* __restrict__ cnt,
    const int* __restrict__ boff, int* __restrict__ off, int* __restrict__ pos,
    int n) {
  int base = blockIdx.x * SCH + threadIdx.x * 4;
  int4 v = make_int4(0, 0, 0, 0);
  if (base + 3 < n) v = *(const int4*)&cnt[base];
  else {
    if (base + 0 < n) v.x = cnt[base + 0];
    if (base + 1 < n) v.y = cnt[base + 1];
    if (base + 2 < n) v.z = cnt[base + 2];
  }
  int s = v.x + v.y + v.z + v.w;
  int lane = threadIdx.x & 63, wv = threadIdx.x >> 6;
  int inc = s;
#pragma unroll
  for (int d = 1; d < 64; d <<= 1) {
    int u = __shfl_up(inc, d);
    if (lane >= d) inc += u;
  }
  __shared__ int wsum[4];
  if (lane == 63) wsum[wv] = inc;
  __syncthreads();
  int wbase = 0;
  for (int i = 0; i < wv; ++i) wbase += wsum[i];
  int ex = boff[blockIdx.x] + wbase + inc - s;
  int4 o = make_int4(ex, ex + v.x, ex + v.x + v.y, ex + v.x + v.y + v.z);
  if (base + 3 < n) {
    *(int4*)&off[base] = o;
    *(int4*)&pos[base] = o;
  } else {
    if (base + 0 < n) { off[base + 0] = o.x; pos[base + 0] = o.x; }
    if (base + 1 < n) { off[base + 1] = o.y; pos[base + 1] = o.y; }
    if (base + 2 < n) { off[base + 2] = o.z; pos[base + 2] = o.z; }
  }
}

// CSR record: 4B = (src << 16) | fp16(w * dinv[src]).
__global__ __launch_bounds__(256) void k_fill(const int* __restrict__ src,
    const int* __restrict__ dst, const float* __restrict__ w,
    const float* __restrict__ dinv, int* __restrict__ pos,
    unsigned int* __restrict__ erec, int E) {
  int e = blockIdx.x * 256 + threadIdx.x;
  if (e < E) {
    int s = src[e], d = dst[e];
    int p = atomicAdd(&pos[d], 1);
    __half u = __float2half(w[e] * dinv[s]);
    erec[p] = ((unsigned)s << 16) | (unsigned)__half_as_ushort(u);
  }
}

// ---------------- W pre-swizzle into MFMA fragment order (fp16) ----------
// Wsw frag index = ((nt*4 + ks)*64 + lane), 8 fp16 each:
// element i = W[ks*32 + (lane>>4)*8 + i][nt*16 + (lane&15)]
template <int NOUT>
__global__ __launch_bounds__(256) void k_wprep(const float* __restrict__ W,
    uint4* __restrict__ Wsw) {
  int tid = blockIdx.x * 256 + threadIdx.x;
  if (tid >= (NOUT / 16) * 4 * 64) return;
  int l = tid & 63, ks = (tid >> 6) & 3, nt = tid >> 8;
  int col = nt * 16 + (l & 15);
  int kbase = ks * 32 + (l >> 4) * 8;
  _Float16 vals[8];
#pragma unroll
  for (int i = 0; i < 8; ++i) vals[i] = (_Float16)W[(kbase + i) * NOUT + col];
  Wsw[tid] = *(uint4*)vals;
}

// ---------------- MFMA GEMM: [n,128] x [128,NOUT] -> fp16 Y --------------
// BM=64 rows/block, 4 waves, each wave owns 16 rows, all NOUT cols.
// X staged as fp16 in XOR-swizzled LDS (MODE fusion during staging).
// MODE 0 plain; MODE 1 bn+relu + residual side-write; MODE 2 bn+relu+res add.

__device__ __forceinline__ unsigned pkh(float a, float b) {
  return (unsigned)__half_as_ushort(__float2half(a)) |
         ((unsigned)__half_as_ushort(__float2half(b)) << 16);
}

#define BM 64
template <int NOUT, int MODE>
__global__ __launch_bounds__(256) void k_gemm(const float* __restrict__ X,
    const uint4* __restrict__ Wsw, unsigned short* __restrict__ Y, int n,
    const float* __restrict__ scsh, const float4* __restrict__ Rres,
    float4* __restrict__ Rout) {
  constexpr int NT = NOUT / 16;
  __shared__ _Float16 xs[BM * 128];
  const int t = threadIdx.x;
  const int row0 = blockIdx.x * BM;
  // stage: 64 rows x 16 chunks of 8 fp16
  for (int i = t; i < BM * 16; i += 256) {
    int r = i >> 4, cg = i & 15;
    bool valid = (row0 + r) < n;
    float4 v0 = make_float4(0.f, 0.f, 0.f, 0.f), v1 = v0;
    if (valid) {
      v0 = ((const float4*)X)[(size_t)(row0 + r) * 32 + cg * 2];
      v1 = ((const float4*)X)[(size_t)(row0 + r) * 32 + cg * 2 + 1];
    }
    if (MODE >= 1) {
      int c0 = cg * 8;
      v0.x = fmaxf(v0.x * scsh[c0 + 0] + scsh[128 + c0 + 0], 0.f);
      v0.y = fmaxf(v0.y * scsh[c0 + 1] + scsh[128 + c0 + 1], 0.f);
      v0.z = fmaxf(v0.z * scsh[c0 + 2] + scsh[128 + c0 + 2], 0.f);
      v0.w = fmaxf(v0.w * scsh[c0 + 3] + scsh[128 + c0 + 3], 0.f);
      v1.x = fmaxf(v1.x * scsh[c0 + 4] + scsh[128 + c0 + 4], 0.f);
      v1.y = fmaxf(v1.y * scsh[c0 + 5] + scsh[128 + c0 + 5], 0.f);
      v1.z = fmaxf(v1.z * scsh[c0 + 6] + scsh[128 + c0 + 6], 0.f);
      v1.w = fmaxf(v1.w * scsh[c0 + 7] + scsh[128 + c0 + 7], 0.f);
      if (MODE == 2 && valid) {
        float4 r0 = Rres[(size_t)(row0 + r) * 32 + cg * 2];
        float4 r1 = Rres[(size_t)(row0 + r) * 32 + cg * 2 + 1];
        v0.x += r0.x; v0.y += r0.y; v0.z += r0.z; v0.w += r0.w;
        v1.x += r1.x; v1.y += r1.y; v1.z += r1.z; v1.w += r1.w;
      }
      if (MODE == 1 && valid) {
        Rout[(size_t)(row0 + r) * 32 + cg * 2] = v0;
        Rout[(size_t)(row0 + r) * 32 + cg * 2 + 1] = v1;
      }
    }
    uint4 pk;
    pk.x = pkh(v0.x, v0.y);
    pk.y = pkh(v0.z, v0.w);
    pk.z = pkh(v1.x, v1.y);
    pk.w = pkh(v1.z, v1.w);
    *(uint4*)&xs[r * 128 + ((cg ^ (r & 15)) << 3)] = pk;
  }
  __syncthreads();

  const int lane = t & 63;
  const int wave = t >> 6;
  const int arow = wave * 16 + (lane & 15);
  // A fragments for all 4 k-steps
  f16x8 a[4];
#pragma unroll
  for (int ks = 0; ks < 4; ++ks) {
    int cg = ks * 4 + (lane >> 4);
    a[ks] = *(const f16x8*)&xs[arow * 128 + ((cg ^ (arow & 15)) << 3)];
  }
  const f16x8* Wf = (const f16x8*)Wsw;
  f32x4 acc[NT];
#pragma unroll
  for (int nt = 0; nt < NT; ++nt) acc[nt] = (f32x4)(0.f);
#pragma unroll
  for (int nt = 0; nt < NT; ++nt) {
#pragma unroll
    for (int ks = 0; ks < 4; ++ks) {
      f16x8 b = Wf[(nt * 4 + ks) * 64 + lane];
      acc[nt] = __builtin_amdgcn_mfma_f32_16x16x32_f16(a[ks], b, acc[nt], 0, 0, 0);
    }
  }
  // D: col = lane&15 (+nt*16), row = wave*16 + (lane>>4)*4 + j
  const int rbase = row0 + wave * 16 + (lane >> 4) * 4;
  const int cbase = lane & 15;
#pragma unroll
  for (int j = 0; j < 4; ++j) {
    int row = rbase + j;
    if (row < n) {
#pragma unroll
      for (int nt = 0; nt < NT; ++nt)
        Y[(size_t)row * NOUT + nt * 16 + cbase] =
            __half_as_ushort(__float2half(acc[nt][j]));
    }
  }
}

// ------------- CSR propagation over fp16 rows: out fp32 ----------------
// out[d] = di * (sum_e u_e*T[src_e] + di*T[d]) + bias,  di = dinv[d].
#define LOH(u) __half2float(__ushort_as_half((unsigned short)((u) & 0xFFFFu)))
#define HIH(u) __half2float(__ushort_as_half((unsigned short)((u) >> 16)))

template <int F>
__global__ __launch_bounds__(256) void k_propb(const uint4* __restrict__ T,
    const float* __restrict__ dinv, const int* __restrict__ off,
    const unsigned int* __restrict__ erec, const float* __restrict__ bias,
    float* __restrict__ out, int n) {
  constexpr int TPN = F / 8;
  constexpr int NPB = 256 / TPN;
  int node = blockIdx.x * NPB + threadIdx.x / TPN;
  int f8 = threadIdx.x % TPN;
  if (node >= n) return;
  float di = dinv[node];
  float acc[8];
  {
    uint4 v = T[(size_t)node * TPN + f8];
    acc[0] = di * LOH(v.x); acc[1] = di * HIH(v.x);
    acc[2] = di * LOH(v.y); acc[3] = di * HIH(v.y);
    acc[4] = di * LOH(v.z); acc[5] = di * HIH(v.z);
    acc[6] = di * LOH(v.w); acc[7] = di * HIH(v.w);
  }
  int e = off[node], eend = off[node + 1];
  for (; e + 1 < eend; e += 2) {
    unsigned r0 = erec[e], r1 = erec[e + 1];
    uint4 v0 = T[(size_t)(r0 >> 16) * TPN + f8];
    uint4 v1 = T[(size_t)(r1 >> 16) * TPN + f8];
    float n0 = LOH(r0), n1 = LOH(r1);
    acc[0] = fmaf(n0, LOH(v0.x), acc[0]); acc[1] = fmaf(n0, HIH(v0.x), acc[1]);
    acc[2] = fmaf(n0, LOH(v0.y), acc[2]); acc[3] = fmaf(n0, HIH(v0.y), acc[3]);
    acc[4] = fmaf(n0, LOH(v0.z), acc[4]); acc[5] = fmaf(n0, HIH(v0.z), acc[5]);
    acc[6] = fmaf(n0, LOH(v0.w), acc[6]); acc[7] = fmaf(n0, HIH(v0.w), acc[7]);
    acc[0] = fmaf(n1, LOH(v1.x), acc[0]); acc[1] = fmaf(n1, HIH(v1.x), acc[1]);
    acc[2] = fmaf(n1, LOH(v1.y), acc[2]); acc[3] = fmaf(n1, HIH(v1.y), acc[3]);
    acc[4] = fmaf(n1, LOH(v1.z), acc[4]); acc[5] = fmaf(n1, HIH(v1.z), acc[5]);
    acc[6] = fmaf(n1, LOH(v1.w), acc[6]); acc[7] = fmaf(n1, HIH(v1.w), acc[7]);
  }
  if (e < eend) {
    unsigned r0 = erec[e];
    uint4 v0 = T[(size_t)(r0 >> 16) * TPN + f8];
    float n0 = LOH(r0);
    acc[0] = fmaf(n0, LOH(v0.x), acc[0]); acc[1] = fmaf(n0, HIH(v0.x), acc[1]);
    acc[2] = fmaf(n0, LOH(v0.y), acc[2]); acc[3] = fmaf(n0, HIH(v0.y), acc[3]);
    acc[4] = fmaf(n0, LOH(v0.z), acc[4]); acc[5] = fmaf(n0, HIH(v0.z), acc[5]);
    acc[6] = fmaf(n0, LOH(v0.w), acc[6]); acc[7] = fmaf(n0, HIH(v0.w), acc[7]);
  }
  float4 b0 = *(const float4*)&bias[f8 * 8];
  float4 b1 = *(const float4*)&bias[f8 * 8 + 4];
  float* op = &out[(size_t)node * F + f8 * 8];
  *(float4*)op = make_float4(fmaf(di, acc[0], b0.x), fmaf(di, acc[1], b0.y),
                             fmaf(di, acc[2], b0.z), fmaf(di, acc[3], b0.w));
  *(float4*)(op + 4) = make_float4(fmaf(di, acc[4], b1.x), fmaf(di, acc[5], b1.y),
                                   fmaf(di, acc[6], b1.z), fmaf(di, acc[7], b1.w));
}

// ---------------- BatchNorm stats ----------------

__global__ __launch_bounds__(128) void k_stats(const float* __restrict__ X,
    float* __restrict__ stats, int n) {
  int col = threadIdx.x;
  float s = 0.f, s2 = 0.f;
  for (int r = blockIdx.x; r < n; r += gridDim.x) {
    float v = X[(size_t)r * 128 + col];
    s += v; s2 += v * v;
  }
  atomicAdd(&stats[col], s);
  atomicAdd(&stats[128 + col], s2);
}

__global__ __launch_bounds__(128) void k_bnfin(const float* __restrict__ stats,
    const float* __restrict__ g, const float* __restrict__ be,
    float* __restrict__ scsh, int n) {
  int c = threadIdx.x;
  float m = stats[c] / (float)n;
  float var = stats[128 + c] / (float)n - m * m;
  var = fmaxf(var, 0.f);
  float sc = g[c] * rsqrtf(var + 1e-5f);
  scsh[c] = sc;
  scsh[128 + c] = be[c] - m * sc;
}

// ---------------- head weight concat + final reparam ----------------

__global__ __launch_bounds__(256) void k_concat(const float* __restrict__ Wm,
    const float* __restrict__ bm, const float* __restrict__ Ws,
    const float* __restrict__ bs, float* __restrict__ wcat,
    float* __restrict__ bcat) {
  int t = blockIdx.x * 256 + threadIdx.x;
  if (t < 128 * 64) {
    int k = t / 64, c = t % 64;
    wcat[t] = (c < 32) ? Wm[k * 32 + c] : Ws[k * 32 + (c - 32)];
  } else if (t < 128 * 64 + 64) {
    int c = t - 128 * 64;
    bcat[c] = (c < 32) ? bm[c] : bs[c - 32];
  }
}

__global__ __launch_bounds__(256) void k_final(const float* __restrict__ agg,
    const float* __restrict__ eps, float* __restrict__ out, int n) {
  int i = blockIdx.x * 256 + threadIdx.x;
  int M = n * 32;
  if (i >= M) return;
  int node = i >> 5, j = i & 31;
  float qm = agg[(size_t)node * 64 + j];
  float qs = agg[(size_t)node * 64 + 32 + j];
  float sp = fmaxf(qs, 0.f) + log1pf(expf(-fabsf(qs)));
  float stdv = sp + 1e-6f;
  out[i] = qm + stdv * eps[i];
  out[M + i] = qm;
  out[2 * M + i] = qs;
}

// ---------------- launch ----------------

extern "C" void kernel_launch(void* const* d_in, const int* in_sizes, int n_in,
                              void* d_out, int out_size, void* d_ws, size_t ws_size,
                              hipStream_t stream) {
  const float* x  = (const float*)d_in[0];
  const int*   ei = (const int*)d_in[1];
  const float* ew = (const float*)d_in[2];
  const float* W0 = (const float*)d_in[3];
  const float* b0 = (const float*)d_in[4];
  const float* W1 = (const float*)d_in[5];
  const float* b1 = (const float*)d_in[6];
  const float* g0 = (const float*)d_in[7];
  const float* be0 = (const float*)d_in[8];
  const float* g1 = (const float*)d_in[9];
  const float* be1 = (const float*)d_in[10];
  const float* Wm = (const float*)d_in[11];
  const float* bm = (const float*)d_in[12];
  const float* Ws = (const float*)d_in[13];
  const float* bs = (const float*)d_in[14];
  const float* eps = (const float*)d_in[15];
  float* out = (float*)d_out;

  const int n = in_sizes[0] / HID;
  const int E = in_sizes[1] / 2;
  const int* esrc = ei;
  const int* edst = ei + E;

  char* base = (char*)d_ws;
  size_t cur = 0;
  auto alloc = [&](size_t bytes) {
    size_t o = cur;
    cur = (cur + bytes + 255) & ~(size_t)255;
    return (void*)(base + o);
  };
  unsigned long long* packed = (unsigned long long*)alloc((size_t)n * 8);
  float* dinv  = (float*)alloc((size_t)n * 4);
  int*   cnt   = (int*)alloc((size_t)n * 4);
  int*   coff  = (int*)alloc((size_t)(n + 1) * 4);
  int*   cpos  = (int*)alloc((size_t)n * 4);
  unsigned int* erec = (unsigned int*)alloc((size_t)E * 4);
  int*   bsum  = (int*)alloc(64 * 4);
  int*   boff  = (int*)alloc(64 * 4);
  float* stats = (float*)alloc(256 * 4);
  float* scsh0 = (float*)alloc(256 * 4);
  float* scsh1 = (float*)alloc(256 * 4);
  float* wcat  = (float*)alloc(128 * 64 * 4);
  float* bcat  = (float*)alloc(64 * 4);
  uint4* Wsw0  = (uint4*)alloc(8 * 4 * 64 * 16);
  uint4* Wsw1  = (uint4*)alloc(8 * 4 * 64 * 16);
  uint4* Wswc  = (uint4*)alloc(4 * 4 * 64 * 16);
  unsigned short* bufA = (unsigned short*)alloc((size_t)n * 128 * 2);  // fp16
  float* bufB  = (float*)alloc((size_t)n * 128 * 4);
  float* bufC  = (float*)alloc((size_t)n * 128 * 4);
  (void)ws_size;

  const int nb = (n + 255) / 256;
  const int eb = (E + 255) / 256;
  const int gemmb = (n + BM - 1) / BM;
  const int scb = (n + SCH - 1) / SCH;
  const int mlat = n * 32;
  const int mlatb = (mlat + 255) / 256;

  // --- norm + CSR ---
  hipMemsetAsync(packed, 0, (size_t)n * 8, stream);
  k_deg_edges<<<eb, 256, 0, stream>>>(edst, ew, packed, E);
  k_dinv<<<nb, 256, 0, stream>>>(packed, dinv, cnt, n);
  k_scan_part<<<scb, 256, 0, stream>>>(cnt, bsum, n);
  k_scan_mid<<<1, 64, 0, stream>>>(bsum, boff, coff, scb, n);
  k_scan_out<<<scb, 256, 0, stream>>>(cnt, boff, coff, cpos, n);
  k_fill<<<eb, 256, 0, stream>>>(esrc, edst, ew, dinv, cpos, erec, E);
  k_concat<<<(128 * 64 + 64 + 255) / 256, 256, 0, stream>>>(Wm, bm, Ws, bs, wcat, bcat);
  k_wprep<128><<<8, 256, 0, stream>>>(W0, Wsw0);
  k_wprep<128><<<8, 256, 0, stream>>>(W1, Wsw1);
  k_wprep<64><<<4, 256, 0, stream>>>(wcat, Wswc);

  // --- layer 0 ---
  k_gemm<128, 0><<<gemmb, 256, 0, stream>>>(x, Wsw0, bufA, n, nullptr, nullptr, nullptr);
  k_propb<128><<<(n + 15) / 16, 256, 0, stream>>>((const uint4*)bufA, dinv, coff,
                                                  erec, b0, bufB, n);
  hipMemsetAsync(stats, 0, 256 * 4, stream);
  k_stats<<<512, 128, 0, stream>>>(bufB, stats, n);
  k_bnfin<<<1, 128, 0, stream>>>(stats, g0, be0, scsh0, n);

  // --- layer 1 (bn0+relu fused into gemm staging; residual h0 -> bufC) ---
  k_gemm<128, 1><<<gemmb, 256, 0, stream>>>(bufB, Wsw1, bufA, n, scsh0, nullptr,
                                            (float4*)bufC);
  k_propb<128><<<(n + 15) / 16, 256, 0, stream>>>((const uint4*)bufA, dinv, coff,
                                                  erec, b1, bufB, n);
  hipMemsetAsync(stats, 0, 256 * 4, stream);
  k_stats<<<512, 128, 0, stream>>>(bufB, stats, n);
  k_bnfin<<<1, 128, 0, stream>>>(stats, g1, be1, scsh1, n);

  // --- heads (bn1+relu+residual fused into gemm staging; mean||logstd) ---
  k_gemm<64, 2><<<gemmb, 256, 0, stream>>>(bufB, Wswc, bufA, n, scsh1,
                                           (const float4*)bufC, nullptr);
  k_propb<64><<<(n + 31) / 32, 256, 0, stream>>>((const uint4*)bufA, dinv, coff,
                                                 erec, bcat, bufB, n);

  // --- reparameterization + output ---
  k_final<<<mlatb, 256, 0, stream>>>(bufB, eps, out, n);
}

// Round 7
// 277.727 us; speedup vs baseline: 1.5899x; 1.1529x over previous
//
#include <hip/hip_runtime.h>
#include <hip/hip_bf16.h>
#include <hip/hip_fp16.h>
#include <math.h>

// GraphEncoderStack: 2x (GCNConv -> BN -> ReLU) + residual + 2 GCN heads + reparam
// N=50000 nodes, E=800000 edges, IN=HIDDEN=128, LATENT=32.
// fp32 math; GEMM via MFMA f16 (fp32 accum); all hidden intermediates fp16.
// Requires n < 65536 (problem fixes n=50000).

#define HID 128
#define LAT 32

typedef _Float16 f16x8 __attribute__((ext_vector_type(8)));
typedef float f32x4 __attribute__((ext_vector_type(4)));

#define LOH(u) __half2float(__ushort_as_half((unsigned short)((u) & 0xFFFFu)))
#define HIH(u) __half2float(__ushort_as_half((unsigned short)((u) >> 16)))

__device__ __forceinline__ unsigned pkh(float a, float b) {
  return (unsigned)__half_as_ushort(__float2half(a)) |
         ((unsigned)__half_as_ushort(__float2half(b)) << 16);
}

// ---------------- degree+count in one packed 64-bit atomic ----------------
// packed[d] += (1<<48)|(w*2^24); old>>48 = this edge's rank within its dst.

__global__ __launch_bounds__(256) void k_deg_edges(const int* __restrict__ dst,
    const float* __restrict__ w, unsigned long long* __restrict__ packed,
    unsigned short* __restrict__ rank, int E) {
  int e = blockIdx.x * 256 + threadIdx.x;
  if (e < E) {
    int d = dst[e];
    unsigned long long v =
        (1ULL << 48) | (unsigned long long)(w[e] * 16777216.0f);
    unsigned long long old = atomicAdd(&packed[d], v);
    rank[e] = (unsigned short)(old >> 48);
  }
}

__global__ __launch_bounds__(256) void k_dinv(
    const unsigned long long* __restrict__ packed, float* __restrict__ dinv,
    int* __restrict__ cnt, int n) {
  int i = blockIdx.x * 256 + threadIdx.x;
  if (i < n) {
    unsigned long long p = packed[i];
    cnt[i] = (int)(p >> 48);
    float d = (float)(p & 0xFFFFFFFFFFFFULL) * (1.0f / 16777216.0f) + 1.0f;
    dinv[i] = rsqrtf(d);
  }
}

// ---------------- hierarchical exclusive scan (n <= 65536) ----------------
#define SCH 1024

__global__ __launch_bounds__(256) void k_scan_part(const int* __restrict__ cnt,
    int* __restrict__ bsum, int n) {
  int base = blockIdx.x * SCH + threadIdx.x * 4;
  int4 v = make_int4(0, 0, 0, 0);
  if (base + 3 < n) v = *(const int4*)&cnt[base];
  else {
    if (base + 0 < n) v.x = cnt[base + 0];
    if (base + 1 < n) v.y = cnt[base + 1];
    if (base + 2 < n) v.z = cnt[base + 2];
  }
  int s = v.x + v.y + v.z + v.w;
#pragma unroll
  for (int off = 32; off; off >>= 1) s += __shfl_down(s, off);
  __shared__ int ws[4];
  if ((threadIdx.x & 63) == 0) ws[threadIdx.x >> 6] = s;
  __syncthreads();
  if (threadIdx.x == 0) bsum[blockIdx.x] = ws[0] + ws[1] + ws[2] + ws[3];
}

__global__ __launch_bounds__(64) void k_scan_mid(const int* __restrict__ bsum,
    int* __restrict__ boff, int* __restrict__ off, int nb, int n) {
  int t = threadIdx.x;
  int val = (t < nb) ? bsum[t] : 0;
  int inc = val;
#pragma unroll
  for (int d = 1; d < 64; d <<= 1) {
    int u = __shfl_up(inc, d);
    if (t >= d) inc += u;
  }
  if (t < nb) boff[t] = inc - val;
  if (t == nb - 1) off[n] = inc;
}

__global__ __launch_bounds__(256) void k_scan_out(const int* __restrict__ cnt,
    const int* __restrict__ boff, int* __restrict__ off, int n) {
  int base = blockIdx.x * SCH + threadIdx.x * 4;
  int4 v = make_int4(0, 0, 0, 0);
  if (base + 3 < n) v = *(const int4*)&cnt[base];
  else {
    if (base + 0 < n) v.x = cnt[base + 0];
    if (base + 1 < n) v.y = cnt[base + 1];
    if (base + 2 < n) v.z = cnt[base + 2];
  }
  int s = v.x + v.y + v.z + v.w;
  int lane = threadIdx.x & 63, wv = threadIdx.x >> 6;
  int inc = s;
#pragma unroll
  for (int d = 1; d < 64; d <<= 1) {
    int u = __shfl_up(inc, d);
    if (lane >= d) inc += u;
  }
  __shared__ int wsum[4];
  if (lane == 63) wsum[wv] = inc;
  __syncthreads();
  int wbase = 0;
  for (int i = 0; i < wv; ++i) wbase += wsum[i];
  int ex = boff[blockIdx.x] + wbase + inc - s;
  int4 o = make_int4(ex, ex + v.x, ex + v.x + v.y, ex + v.x + v.y + v.z);
  if (base + 3 < n) {
    *(int4*)&off[base] = o;
  } else {
    if (base + 0 < n) off[base + 0] = o.x;
    if (base + 1 < n) off[base + 1] = o.y;
    if (base + 2 < n) off[base + 2] = o.z;
  }
}

// CSR record: 4B = (src << 16) | fp16(w * dinv[src]).  No atomic: position
// = coff[dst] + rank (rank captured from the degree pass's atomic return).
__global__ __launch_bounds__(256) void k_fill(const int* __restrict__ src,
    const int* __restrict__ dst, const float* __restrict__ w,
    const float* __restrict__ dinv, const int* __restrict__ coff,
    const unsigned short* __restrict__ rank, unsigned int* __restrict__ erec,
    int E) {
  int e = blockIdx.x * 256 + threadIdx.x;
  if (e < E) {
    int s = src[e], d = dst[e];
    int p = coff[d] + (int)rank[e];
    __half u = __float2half(w[e] * dinv[s]);
    erec[p] = ((unsigned)s << 16) | (unsigned)__half_as_ushort(u);
  }
}

// ---------------- W pre-swizzle into MFMA fragment order (fp16) ----------
template <int NOUT>
__global__ __launch_bounds__(256) void k_wprep(const float* __restrict__ W,
    uint4* __restrict__ Wsw) {
  int tid = blockIdx.x * 256 + threadIdx.x;
  if (tid >= (NOUT / 16) * 4 * 64) return;
  int l = tid & 63, ks = (tid >> 6) & 3, nt = tid >> 8;
  int col = nt * 16 + (l & 15);
  int kbase = ks * 32 + (l >> 4) * 8;
  _Float16 vals[8];
#pragma unroll
  for (int i = 0; i < 8; ++i) vals[i] = (_Float16)W[(kbase + i) * NOUT + col];
  Wsw[tid] = *(uint4*)vals;
}

// ---------------- MFMA GEMM: [n,128] x [128,NOUT] -> fp16 Y --------------
// BM=64 rows/block, 4 waves; wave owns 16 rows x NOUT cols.
// MODE 0: fp32 X, plain. MODE 1: fp16 X, bn+relu, residual side-write (fp16).
// MODE 2: fp16 X, bn+relu+residual add (fp16).

#define BM 64
template <int NOUT, int MODE>
__global__ __launch_bounds__(256) void k_gemm(const void* __restrict__ Xv,
    const uint4* __restrict__ Wsw, unsigned short* __restrict__ Y, int n,
    const float* __restrict__ scsh, const uint4* __restrict__ Rres,
    uint4* __restrict__ Rout) {
  constexpr int NT = NOUT / 16;
  __shared__ _Float16 xs[BM * 128];
  const int t = threadIdx.x;
  const int row0 = blockIdx.x * BM;
  for (int i = t; i < BM * 16; i += 256) {
    int r = i >> 4, cg = i & 15;
    bool valid = (row0 + r) < n;
    float f[8];
    if (MODE == 0) {
      float4 v0 = make_float4(0.f, 0.f, 0.f, 0.f), v1 = v0;
      if (valid) {
        v0 = ((const float4*)Xv)[(size_t)(row0 + r) * 32 + cg * 2];
        v1 = ((const float4*)Xv)[(size_t)(row0 + r) * 32 + cg * 2 + 1];
      }
      f[0] = v0.x; f[1] = v0.y; f[2] = v0.z; f[3] = v0.w;
      f[4] = v1.x; f[5] = v1.y; f[6] = v1.z; f[7] = v1.w;
    } else {
      uint4 h = valid ? ((const uint4*)Xv)[(size_t)(row0 + r) * 16 + cg]
                      : make_uint4(0, 0, 0, 0);
      f[0] = LOH(h.x); f[1] = HIH(h.x); f[2] = LOH(h.y); f[3] = HIH(h.y);
      f[4] = LOH(h.z); f[5] = HIH(h.z); f[6] = LOH(h.w); f[7] = HIH(h.w);
    }
    if (MODE >= 1) {
      int c0 = cg * 8;
#pragma unroll
      for (int j = 0; j < 8; ++j)
        f[j] = fmaxf(f[j] * scsh[c0 + j] + scsh[128 + c0 + j], 0.f);
      if (MODE == 2 && valid) {
        uint4 rr = Rres[(size_t)(row0 + r) * 16 + cg];
        f[0] += LOH(rr.x); f[1] += HIH(rr.x);
        f[2] += LOH(rr.y); f[3] += HIH(rr.y);
        f[4] += LOH(rr.z); f[5] += HIH(rr.z);
        f[6] += LOH(rr.w); f[7] += HIH(rr.w);
      }
    }
    uint4 pk;
    pk.x = pkh(f[0], f[1]);
    pk.y = pkh(f[2], f[3]);
    pk.z = pkh(f[4], f[5]);
    pk.w = pkh(f[6], f[7]);
    if (MODE == 1 && valid) Rout[(size_t)(row0 + r) * 16 + cg] = pk;
    *(uint4*)&xs[r * 128 + ((cg ^ (r & 15)) << 3)] = pk;
  }
  __syncthreads();

  const int lane = t & 63;
  const int wave = t >> 6;
  const int arow = wave * 16 + (lane & 15);
  f16x8 a[4];
#pragma unroll
  for (int ks = 0; ks < 4; ++ks) {
    int cg = ks * 4 + (lane >> 4);
    a[ks] = *(const f16x8*)&xs[arow * 128 + ((cg ^ (arow & 15)) << 3)];
  }
  const f16x8* Wf = (const f16x8*)Wsw;
  f32x4 acc[NT];
#pragma unroll
  for (int nt = 0; nt < NT; ++nt) acc[nt] = (f32x4)(0.f);
#pragma unroll
  for (int nt = 0; nt < NT; ++nt) {
#pragma unroll
    for (int ks = 0; ks < 4; ++ks) {
      f16x8 b = Wf[(nt * 4 + ks) * 64 + lane];
      acc[nt] = __builtin_amdgcn_mfma_f32_16x16x32_f16(a[ks], b, acc[nt], 0, 0, 0);
    }
  }
  const int rbase = row0 + wave * 16 + (lane >> 4) * 4;
  const int cbase = lane & 15;
#pragma unroll
  for (int j = 0; j < 4; ++j) {
    int row = rbase + j;
    if (row < n) {
#pragma unroll
      for (int nt = 0; nt < NT; ++nt)
        Y[(size_t)row * NOUT + nt * 16 + cbase] =
            __half_as_ushort(__float2half(acc[nt][j]));
    }
  }
}

// ------------- CSR propagation over fp16 rows ----------------
// out[d] = di * (sum_e u_e*T[src_e] + di*T[d]) + bias,  di = dinv[d].
// OUT16: pack result to fp16; else fp32.
template <int F, int OUT16>
__global__ __launch_bounds__(256) void k_propb(const uint4* __restrict__ T,
    const float* __restrict__ dinv, const int* __restrict__ off,
    const unsigned int* __restrict__ erec, const float* __restrict__ bias,
    void* __restrict__ outv, int n) {
  constexpr int TPN = F / 8;
  constexpr int NPB = 256 / TPN;
  int node = blockIdx.x * NPB + threadIdx.x / TPN;
  int f8 = threadIdx.x % TPN;
  if (node >= n) return;
  float di = dinv[node];
  float acc[8];
  {
    uint4 v = T[(size_t)node * TPN + f8];
    acc[0] = di * LOH(v.x); acc[1] = di * HIH(v.x);
    acc[2] = di * LOH(v.y); acc[3] = di * HIH(v.y);
    acc[4] = di * LOH(v.z); acc[5] = di * HIH(v.z);
    acc[6] = di * LOH(v.w); acc[7] = di * HIH(v.w);
  }
  int e = off[node], eend = off[node + 1];
  for (; e + 1 < eend; e += 2) {
    unsigned r0 = erec[e], r1 = erec[e + 1];
    uint4 v0 = T[(size_t)(r0 >> 16) * TPN + f8];
    uint4 v1 = T[(size_t)(r1 >> 16) * TPN + f8];
    float n0 = LOH(r0), n1 = LOH(r1);
    acc[0] = fmaf(n0, LOH(v0.x), acc[0]); acc[1] = fmaf(n0, HIH(v0.x), acc[1]);
    acc[2] = fmaf(n0, LOH(v0.y), acc[2]); acc[3] = fmaf(n0, HIH(v0.y), acc[3]);
    acc[4] = fmaf(n0, LOH(v0.z), acc[4]); acc[5] = fmaf(n0, HIH(v0.z), acc[5]);
    acc[6] = fmaf(n0, LOH(v0.w), acc[6]); acc[7] = fmaf(n0, HIH(v0.w), acc[7]);
    acc[0] = fmaf(n1, LOH(v1.x), acc[0]); acc[1] = fmaf(n1, HIH(v1.x), acc[1]);
    acc[2] = fmaf(n1, LOH(v1.y), acc[2]); acc[3] = fmaf(n1, HIH(v1.y), acc[3]);
    acc[4] = fmaf(n1, LOH(v1.z), acc[4]); acc[5] = fmaf(n1, HIH(v1.z), acc[5]);
    acc[6] = fmaf(n1, LOH(v1.w), acc[6]); acc[7] = fmaf(n1, HIH(v1.w), acc[7]);
  }
  if (e < eend) {
    unsigned r0 = erec[e];
    uint4 v0 = T[(size_t)(r0 >> 16) * TPN + f8];
    float n0 = LOH(r0);
    acc[0] = fmaf(n0, LOH(v0.x), acc[0]); acc[1] = fmaf(n0, HIH(v0.x), acc[1]);
    acc[2] = fmaf(n0, LOH(v0.y), acc[2]); acc[3] = fmaf(n0, HIH(v0.y), acc[3]);
    acc[4] = fmaf(n0, LOH(v0.z), acc[4]); acc[5] = fmaf(n0, HIH(v0.z), acc[5]);
    acc[6] = fmaf(n0, LOH(v0.w), acc[6]); acc[7] = fmaf(n0, HIH(v0.w), acc[7]);
  }
  float4 b0 = *(const float4*)&bias[f8 * 8];
  float4 b1 = *(const float4*)&bias[f8 * 8 + 4];
  float r0 = fmaf(di, acc[0], b0.x), r1 = fmaf(di, acc[1], b0.y);
  float r2 = fmaf(di, acc[2], b0.z), r3 = fmaf(di, acc[3], b0.w);
  float r4 = fmaf(di, acc[4], b1.x), r5 = fmaf(di, acc[5], b1.y);
  float r6 = fmaf(di, acc[6], b1.z), r7 = fmaf(di, acc[7], b1.w);
  if (OUT16) {
    uint4 pk;
    pk.x = pkh(r0, r1); pk.y = pkh(r2, r3);
    pk.z = pkh(r4, r5); pk.w = pkh(r6, r7);
    ((uint4*)outv)[(size_t)node * TPN + f8] = pk;
  } else {
    float* op = (float*)outv + (size_t)node * F + f8 * 8;
    *(float4*)op = make_float4(r0, r1, r2, r3);
    *(float4*)(op + 4) = make_float4(r4, r5, r6, r7);
  }
}

// ---------------- BatchNorm stats over fp16 matrix ----------------

__global__ __launch_bounds__(128) void k_stats(
    const unsigned short* __restrict__ X, float* __restrict__ stats, int n) {
  int col = threadIdx.x;
  float s = 0.f, s2 = 0.f;
  for (int r = blockIdx.x; r < n; r += gridDim.x) {
    float v = __half2float(__ushort_as_half(X[(size_t)r * 128 + col]));
    s += v; s2 += v * v;
  }
  atomicAdd(&stats[col], s);
  atomicAdd(&stats[128 + col], s2);
}

__global__ __launch_bounds__(128) void k_bnfin(const float* __restrict__ stats,
    const float* __restrict__ g, const float* __restrict__ be,
    float* __restrict__ scsh, int n) {
  int c = threadIdx.x;
  float m = stats[c] / (float)n;
  float var = stats[128 + c] / (float)n - m * m;
  var = fmaxf(var, 0.f);
  float sc = g[c] * rsqrtf(var + 1e-5f);
  scsh[c] = sc;
  scsh[128 + c] = be[c] - m * sc;
}

// ---------------- head weight concat + final reparam ----------------

__global__ __launch_bounds__(256) void k_concat(const float* __restrict__ Wm,
    const float* __restrict__ bm, const float* __restrict__ Ws,
    const float* __restrict__ bs, float* __restrict__ wcat,
    float* __restrict__ bcat) {
  int t = blockIdx.x * 256 + threadIdx.x;
  if (t < 128 * 64) {
    int k = t / 64, c = t % 64;
    wcat[t] = (c < 32) ? Wm[k * 32 + c] : Ws[k * 32 + (c - 32)];
  } else if (t < 128 * 64 + 64) {
    int c = t - 128 * 64;
    bcat[c] = (c < 32) ? bm[c] : bs[c - 32];
  }
}

__global__ __launch_bounds__(256) void k_final(const float* __restrict__ agg,
    const float* __restrict__ eps, float* __restrict__ out, int n) {
  int i = blockIdx.x * 256 + threadIdx.x;
  int M = n * 32;
  if (i >= M) return;
  int node = i >> 5, j = i & 31;
  float qm = agg[(size_t)node * 64 + j];
  float qs = agg[(size_t)node * 64 + 32 + j];
  float sp = fmaxf(qs, 0.f) + log1pf(expf(-fabsf(qs)));
  float stdv = sp + 1e-6f;
  out[i] = qm + stdv * eps[i];
  out[M + i] = qm;
  out[2 * M + i] = qs;
}

// ---------------- launch ----------------

extern "C" void kernel_launch(void* const* d_in, const int* in_sizes, int n_in,
                              void* d_out, int out_size, void* d_ws, size_t ws_size,
                              hipStream_t stream) {
  const float* x  = (const float*)d_in[0];
  const int*   ei = (const int*)d_in[1];
  const float* ew = (const float*)d_in[2];
  const float* W0 = (const float*)d_in[3];
  const float* b0 = (const float*)d_in[4];
  const float* W1 = (const float*)d_in[5];
  const float* b1 = (const float*)d_in[6];
  const float* g0 = (const float*)d_in[7];
  const float* be0 = (const float*)d_in[8];
  const float* g1 = (const float*)d_in[9];
  const float* be1 = (const float*)d_in[10];
  const float* Wm = (const float*)d_in[11];
  const float* bm = (const float*)d_in[12];
  const float* Ws = (const float*)d_in[13];
  const float* bs = (const float*)d_in[14];
  const float* eps = (const float*)d_in[15];
  float* out = (float*)d_out;

  const int n = in_sizes[0] / HID;
  const int E = in_sizes[1] / 2;
  const int* esrc = ei;
  const int* edst = ei + E;

  char* base = (char*)d_ws;
  size_t cur = 0;
  auto alloc = [&](size_t bytes) {
    size_t o = cur;
    cur = (cur + bytes + 255) & ~(size_t)255;
    return (void*)(base + o);
  };
  unsigned long long* packed = (unsigned long long*)alloc((size_t)n * 8);
  float* dinv  = (float*)alloc((size_t)n * 4);
  int*   cnt   = (int*)alloc((size_t)n * 4);
  int*   coff  = (int*)alloc((size_t)(n + 1) * 4);
  unsigned short* rank = (unsigned short*)alloc((size_t)E * 2);
  unsigned int* erec = (unsigned int*)alloc((size_t)E * 4);
  int*   bsum  = (int*)alloc(64 * 4);
  int*   boff  = (int*)alloc(64 * 4);
  float* stats = (float*)alloc(256 * 4);
  float* scsh0 = (float*)alloc(256 * 4);
  float* scsh1 = (float*)alloc(256 * 4);
  float* wcat  = (float*)alloc(128 * 64 * 4);
  float* bcat  = (float*)alloc(64 * 4);
  uint4* Wsw0  = (uint4*)alloc(8 * 4 * 64 * 16);
  uint4* Wsw1  = (uint4*)alloc(8 * 4 * 64 * 16);
  uint4* Wswc  = (uint4*)alloc(4 * 4 * 64 * 16);
  unsigned short* bufA = (unsigned short*)alloc((size_t)n * 128 * 2);  // fp16
  unsigned short* bufB = (unsigned short*)alloc((size_t)n * 128 * 2);  // fp16
  unsigned short* bufC = (unsigned short*)alloc((size_t)n * 128 * 2);  // fp16 residual
  float* bufD  = (float*)alloc((size_t)n * 64 * 4);                    // fp32 heads out
  (void)ws_size;

  const int nb = (n + 255) / 256;
  const int eb = (E + 255) / 256;
  const int gemmb = (n + BM - 1) / BM;
  const int scb = (n + SCH - 1) / SCH;
  const int mlat = n * 32;
  const int mlatb = (mlat + 255) / 256;

  // --- norm + CSR ---
  hipMemsetAsync(packed, 0, (size_t)n * 8, stream);
  k_deg_edges<<<eb, 256, 0, stream>>>(edst, ew, packed, rank, E);
  k_dinv<<<nb, 256, 0, stream>>>(packed, dinv, cnt, n);
  k_scan_part<<<scb, 256, 0, stream>>>(cnt, bsum, n);
  k_scan_mid<<<1, 64, 0, stream>>>(bsum, boff, coff, scb, n);
  k_scan_out<<<scb, 256, 0, stream>>>(cnt, boff, coff, n);
  k_fill<<<eb, 256, 0, stream>>>(esrc, edst, ew, dinv, coff, rank, erec, E);
  k_concat<<<(128 * 64 + 64 + 255) / 256, 256, 0, stream>>>(Wm, bm, Ws, bs, wcat, bcat);
  k_wprep<128><<<8, 256, 0, stream>>>(W0, Wsw0);
  k_wprep<128><<<8, 256, 0, stream>>>(W1, Wsw1);
  k_wprep<64><<<4, 256, 0, stream>>>(wcat, Wswc);

  // --- layer 0 ---
  k_gemm<128, 0><<<gemmb, 256, 0, stream>>>(x, Wsw0, bufA, n, nullptr, nullptr, nullptr);
  k_propb<128, 1><<<(n + 15) / 16, 256, 0, stream>>>((const uint4*)bufA, dinv, coff,
                                                     erec, b0, bufB, n);
  hipMemsetAsync(stats, 0, 256 * 4, stream);
  k_stats<<<512, 128, 0, stream>>>(bufB, stats, n);
  k_bnfin<<<1, 128, 0, stream>>>(stats, g0, be0, scsh0, n);

  // --- layer 1 (bn0+relu fused into gemm staging; residual h0 -> bufC fp16) ---
  k_gemm<128, 1><<<gemmb, 256, 0, stream>>>(bufB, Wsw1, bufA, n, scsh0, nullptr,
                                            (uint4*)bufC);
  k_propb<128, 1><<<(n + 15) / 16, 256, 0, stream>>>((const uint4*)bufA, dinv, coff,
                                                     erec, b1, bufB, n);
  hipMemsetAsync(stats, 0, 256 * 4, stream);
  k_stats<<<512, 128, 0, stream>>>(bufB, stats, n);
  k_bnfin<<<1, 128, 0, stream>>>(stats, g1, be1, scsh1, n);

  // --- heads (bn1+relu+residual fused into gemm staging; mean||logstd) ---
  k_gemm<64, 2><<<gemmb, 256, 0, stream>>>(bufB, Wswc, bufA, n, scsh1,
                                           (const uint4*)bufC, nullptr);
  k_propb<64, 0><<<(n + 31) / 32, 256, 0, stream>>>((const uint4*)bufA, dinv, coff,
                                                    erec, bcat, bufD, n);

  // --- reparameterization + output ---
  k_final<<<mlatb, 256, 0, stream>>>(bufD, eps, out, n);
}